// Round 16
// baseline (116.624 us; speedup 1.0000x reference)
//
#include <hip/hip_runtime.h>
#include <hip/hip_fp16.h>

#define L_LEN 8192
#define N_FFT 16384   // 2*L
#define NB    1024

#define LB __launch_bounds__(NB)

// 2-wide float vector = one complex value (re, im).
typedef float f2 __attribute__((ext_vector_type(2)));

__device__ __forceinline__ f2 mkf2(float a, float b) { f2 v; v.x = a; v.y = b; return v; }

__device__ __forceinline__ f2 cmul(f2 a, f2 w) {
    return mkf2(a.y, a.y) * mkf2(-w.y, w.x) + mkf2(a.x, a.x) * w;
}

// ---- fp16x2 packed LDS element (64 KiB total -> 2 blocks/CU) ----
__device__ __forceinline__ unsigned pk16(f2 v) {
    __half2 h = __float22half2_rn(make_float2(v.x, v.y));
    unsigned u; __builtin_memcpy(&u, &h, 4); return u;
}
__device__ __forceinline__ f2 up16(unsigned u) {
    __half2 h; __builtin_memcpy(&h, &u, 4);
    float2 f = __half22float2(h);
    return mkf2(f.x, f.y);
}

// Native hardware sin/cos in REVOLUTIONS; twiddle args are exact dyadic
// rationals with |rev| <= 1/4 -> no range reduction needed.
__device__ __forceinline__ void sincos_rev(float rev, float* sn, float* cs) {
    *sn = __builtin_amdgcn_sinf(rev);
    *cs = __builtin_amdgcn_cosf(rev);
}
__device__ __forceinline__ f2 cis_rev(float rev) {
    return mkf2(__builtin_amdgcn_cosf(rev), __builtin_amdgcn_sinf(rev));
}

// GF(2)-linear swizzle for 32 x b32 banks: swz(a^b)=swz(a)^swz(b) for
// disjoint fields; identity below 32 (preserves the combo's ^k algebra).
__host__ __device__ constexpr int swz(int i) {
    return i ^ ((((i) >> 5) ^ ((i) >> 10)) & 31);
}

// reverse 6 base-4 digits (12-bit input)
__device__ __forceinline__ int rev6(int m) {
    int r = 0;
#pragma unroll
    for (int d = 0; d < 6; ++d) { r = (r << 2) | (m & 3); m >>= 2; }
    return r;
}

// DIF radix-4 butterfly (forward), twiddles precomputed.
__device__ __forceinline__ void bfly_dif(f2& x0, f2& x1, f2& x2, f2& x3,
                                         f2 w1, f2 w2, f2 w3) {
    f2 A = x0 + x2, B = x0 - x2, C = x1 + x3, D = x1 - x3;
    f2 iD = mkf2(-D.y, D.x);
    x0 = A + C;
    x1 = cmul(B - iD, w1);
    x2 = cmul(A - C, w2);
    x3 = cmul(B + iD, w3);
}

// DIT radix-4 butterfly (inverse).
__device__ __forceinline__ void bfly_dit(f2& x0, f2& x1, f2& x2, f2& x3,
                                         f2 w1, f2 w2, f2 w3) {
    f2 a1 = cmul(x1, w1), a2 = cmul(x2, w2), a3 = cmul(x3, w3);
    f2 E = x0 + a2, F = x0 - a2, G = a1 + a3, K = a1 - a3;
    f2 iK = mkf2(-K.y, K.x);
    x0 = E + G; x1 = F + iK; x2 = E - G; x3 = F - iK;
}

__device__ __forceinline__ void bfly_dif1(f2* z) {
    f2 A = z[0] + z[2], B = z[0] - z[2], C = z[1] + z[3], D = z[1] - z[3];
    f2 iD = mkf2(-D.y, D.x);
    z[0] = A + C; z[1] = B - iD; z[2] = A - C; z[3] = B + iD;
}

// Y[m]/16 = (X[m]*H[m])/16 — the 1/16 scale keeps Y in fp16 range and is
// repaid in inv_last's residual scale. (0.125^2 / 0.5^2 = 1/16.)
__device__ __forceinline__ f2 pwY(f2 Zm, f2 Zr) {
    f2 q = mkf2(0.125f, 0.125f);
    f2 X = q * (Zm + mkf2(Zr.x, -Zr.y));
    f2 H = q * (mkf2(Zm.y, -Zm.x) + mkf2(Zr.y, Zr.x));
    return cmul(X, H);
}

// cos/sin of 2*pi*j/16, j=0..3
#define CT0 1.0f
#define CT1 0.92387953251128674f
#define CT2 0.70710678118654752f
#define CT3 0.38268343236508977f
#define ST1 0.38268343236508977f
#define ST2 0.70710678118654752f
#define ST3 0.92387953251128674f

// First forward double-stage (q=4096,1024) fused with global load; upper
// input half is the zero-pad (x2=x3=0 in the q=4096 butterfly). Unscaled.
__device__ __forceinline__ void fwd_first(unsigned* lds, int tid,
                                          const float* __restrict__ xr,
                                          const float* __restrict__ hr) {
    f2 r[4][4];
    float snA, csA;
    sincos_rev((float)tid * (-1.0f / 16384.f), &snA, &csA);
    f2 u1 = mkf2(csA, snA);
    const f2 lad[4] = {mkf2(CT0, 0.f), mkf2(CT1, -ST1), mkf2(CT2, -ST2), mkf2(CT3, -ST3)};
#pragma unroll
    for (int jB = 0; jB < 4; ++jB) {
        const int t = tid + jB * 1024;
        f2 z0 = mkf2(xr[t], hr[t]);
        f2 z1 = mkf2(xr[t + 4096], hr[t + 4096]);
        f2 w1 = (jB == 0) ? u1 : cmul(u1, lad[jB]);
        f2 w2 = cmul(w1, w1);
        f2 w3 = cmul(w2, w1);
        f2 iz1 = mkf2(-z1.y, z1.x);
        r[0][jB] = z0 + z1;
        r[1][jB] = cmul(z0 - iz1, w1);
        r[2][jB] = cmul(z0 - z1, w2);
        r[3][jB] = cmul(z0 + iz1, w3);
    }
    float sn, cs;
    sincos_rev((float)tid * (-1.0f / 4096.f), &sn, &cs);
    f2 v1 = mkf2(cs, sn);
    f2 v2 = cmul(v1, v1);
    f2 v3 = cmul(v2, v1);
#pragma unroll
    for (int jA = 0; jA < 4; ++jA)
        bfly_dif(r[jA][0], r[jA][1], r[jA][2], r[jA][3], v1, v2, v3);

    const int sb = swz(tid);
#pragma unroll
    for (int jA = 0; jA < 4; ++jA)
#pragma unroll
        for (int jB = 0; jB < 4; ++jB)
            lds[sb ^ swz(jA * 4096 + jB * 1024)] = pk16(r[jA][jB]);
}

// Fused forward DIF pair: stage q=QA then q=QA/4. Unscaled.
template<int QA>
__device__ __forceinline__ void fwd_pair(unsigned* lds, int tid) {
    constexpr int QB = QA / 4;
    const int g = tid / QB;
    const int u = tid % QB;
    const int sb = swz(g * (4 * QA) + u);
    f2 r[4][4];
#pragma unroll
    for (int jA = 0; jA < 4; ++jA)
#pragma unroll
        for (int jB = 0; jB < 4; ++jB)
            r[jA][jB] = up16(lds[sb ^ swz(jA * QA + jB * QB)]);

    {
        float sn, cs;
        sincos_rev((float)u * (-1.0f / (float)(4 * QA)), &sn, &cs);
        f2 u1 = mkf2(cs, sn);
        const f2 lad[4] = {mkf2(CT0, 0.f), mkf2(CT1, -ST1), mkf2(CT2, -ST2), mkf2(CT3, -ST3)};
#pragma unroll
        for (int jB = 0; jB < 4; ++jB) {
            f2 w1 = (jB == 0) ? u1 : cmul(u1, lad[jB]);
            f2 w2 = cmul(w1, w1);
            f2 w3 = cmul(w2, w1);
            bfly_dif(r[0][jB], r[1][jB], r[2][jB], r[3][jB], w1, w2, w3);
        }
    }
    {
        float sn, cs;
        sincos_rev((float)u * (-1.0f / (float)(4 * QB)), &sn, &cs);
        f2 v1 = mkf2(cs, sn);
        f2 v2 = cmul(v1, v1);
        f2 v3 = cmul(v2, v1);
#pragma unroll
        for (int jA = 0; jA < 4; ++jA)
            bfly_dif(r[jA][0], r[jA][1], r[jA][2], r[jA][3], v1, v2, v3);
    }

#pragma unroll
    for (int jA = 0; jA < 4; ++jA)
#pragma unroll
        for (int jB = 0; jB < 4; ++jB)
            lds[sb ^ swz(jA * QA + jB * QB)] = pk16(r[jA][jB]);
}

// ---- combo item: finish fwd (q=1), Y=XH (scaled 1/16), build Zi[j] for the
// half-size inverse: Zi[j] = (Y[j]+Y[j+8192]) + i e^{2pi i j/N}(Y[j]-Y[j+8192]).
__device__ __forceinline__ void combo_item(const unsigned* lds, int b, f2* Zi, int* sl) {
    const int sA = swz(4 * rev6(b));
    const int sB = swz(4 * rev6(4096 - b));
    f2 A[4], B[4];
#pragma unroll
    for (int k = 0; k < 4; ++k) { A[k] = up16(lds[sA ^ k]); B[k] = up16(lds[sB ^ k]); }
    bfly_dif1(A);
    bfly_dif1(B);
    f2 Yb   = pwY(A[0], B[3]);   // Y[b]/16
    f2 Yb4  = pwY(A[1], B[2]);   // Y[4096+b]/16
    f2 Yb8  = pwY(A[2], B[1]);   // Y[8192+b]/16
    f2 Yb12 = pwY(A[3], B[0]);   // Y[12288+b]/16
    f2 t = cis_rev((float)b * (1.0f / 16384.f));   // e^{+2pi i b/N}
    f2 S  = Yb + Yb8,   D  = Yb - Yb8;
    f2 Sp = Yb4 + Yb12, Dp = Yb4 - Yb12;
    f2 c  = cmul(D, t);
    f2 cp = cmul(Dp, t);
    Zi[0] = mkf2(S.x - c.y,    S.y + c.x);       // j = b
    Zi[1] = Sp - cp;                             // j = 4096+b
    Zi[2] = mkf2(Sp.x + cp.x, -(Sp.y + cp.y));   // j = 4096-b
    Zi[3] = mkf2(S.x + c.y,   -S.y + c.x);       // j = 8192-b
    const int sbase = (b & 1) ? swz(4096) : 0;
    const int ra = rev6(b >> 1);                 // ra % 4 == 0
    const int rc = rev6((4096 - b) >> 1);        // rc bit1 free
    sl[0] = sbase ^ swz(ra);
    sl[1] = sl[0] ^ 2;
    sl[2] = sbase ^ swz(rc);
    sl[3] = sl[2] ^ 2;
}

// specials: j in {0, 4096} (quad a=0) and {2048, 6144} (quad a=2); all Y
// terms carry the same 1/16 scale.
__device__ __forceinline__ void combo_special(const unsigned* lds, f2* Zi, int* sl) {
    f2 z[4];
#pragma unroll
    for (int k = 0; k < 4; ++k) z[k] = up16(lds[k]);
    bfly_dif1(z);
    float Y0 = 0.0625f * z[0].x * z[0].y;
    float Y8 = 0.0625f * z[2].x * z[2].y;
    f2 Y4096 = pwY(z[1], z[3]);
    Zi[0] = mkf2(Y0 + Y8, Y0 - Y8);              sl[0] = 0;
    Zi[1] = mkf2(2.f * Y4096.x, -2.f * Y4096.y); sl[1] = 2;
    f2 w[4];
#pragma unroll
    for (int k = 0; k < 4; ++k) w[k] = up16(lds[8 + k]);
    bfly_dif1(w);
    f2 Y2048 = pwY(w[0], w[3]);
    f2 Y6144 = pwY(w[1], w[2]);
    f2 cj6 = mkf2(Y6144.x, -Y6144.y);
    f2 S1 = Y2048 + cj6, D1 = Y2048 - cj6;
    f2 t1 = mkf2(0.70710678118654752f, 0.70710678118654752f);
    f2 c1 = cmul(D1, t1);
    Zi[2] = mkf2(S1.x - c1.y, S1.y + c1.x);  sl[2] = 1;
    f2 cj2 = mkf2(Y2048.x, -Y2048.y);
    f2 S2 = Y6144 + cj2, D2 = Y6144 - cj2;
    f2 t2 = mkf2(-0.70710678118654752f, 0.70710678118654752f);
    f2 c2 = cmul(D2, t2);
    Zi[3] = mkf2(S2.x - c2.y, S2.y + c2.x);  sl[3] = 3;
}

// Fused inverse DIT pair (q=QA then 4*QA) on one 4096-point half; outputs
// scaled by 1/16 (distributed scaling keeps fp16 in range).
template<int QA>
__device__ __forceinline__ void inv_half(unsigned* lds, int th) {
    constexpr int QB = 4 * QA;
    const int h = th >> 8;
    const int k = th & 255;
    const int g = k / QA, u = k % QA;
    const int base = g * (16 * QA) + u;
    const int sb = (h ? swz(4096) : 0) ^ swz(base);
    f2 r[4][4];
#pragma unroll
    for (int jA = 0; jA < 4; ++jA)
#pragma unroll
        for (int jB = 0; jB < 4; ++jB)
            r[jA][jB] = up16(lds[sb ^ swz(jA * QA + jB * QB)]);

    {
        f2 a1;
        if constexpr (QA == 1) a1 = mkf2(1.f, 0.f);
        else { float sn, cs; sincos_rev((float)u * (1.0f / (float)(4 * QA)), &sn, &cs); a1 = mkf2(cs, sn); }
        f2 a2 = cmul(a1, a1), a3 = cmul(a2, a1);
#pragma unroll
        for (int jB = 0; jB < 4; ++jB)
            bfly_dit(r[0][jB], r[1][jB], r[2][jB], r[3][jB], a1, a2, a3);
    }
    {
        f2 b1;
        if constexpr (QA == 1) b1 = mkf2(1.f, 0.f);
        else { float sn, cs; sincos_rev((float)u * (1.0f / (float)(16 * QA)), &sn, &cs); b1 = mkf2(cs, sn); }
        const f2 lad[4] = {mkf2(CT0, 0.f), mkf2(CT1, ST1), mkf2(CT2, ST2), mkf2(CT3, ST3)};
#pragma unroll
        for (int jA = 0; jA < 4; ++jA) {
            f2 w1 = (jA == 0) ? b1 : cmul(b1, lad[jA]);
            f2 w2 = cmul(w1, w1), w3 = cmul(w2, w1);
            bfly_dit(r[jA][0], r[jA][1], r[jA][2], r[jA][3], w1, w2, w3);
        }
    }
    const f2 s = mkf2(0.0625f, 0.0625f);
#pragma unroll
    for (int jA = 0; jA < 4; ++jA)
#pragma unroll
        for (int jB = 0; jB < 4; ++jB)
            lds[sb ^ swz(jA * QA + jB * QB)] = pk16(r[jA][jB] * s);
}

// Final radix-2 + residual scale + store. Scales so far: combo 2^-4 x three
// inverse pairs 2^-4 each = 2^-16; residual 2^-12 gives the full 2^-28.
__device__ __forceinline__ void inv_last(const unsigned* lds, int tid,
                                         float* __restrict__ orow) {
    const float sc = 1.0f / 4096.f;   // 2^-12 residual
    const int s4096 = swz(4096);
#pragma unroll
    for (int i = 0; i < 4; ++i) {
        const int m = tid + i * 1024;
        const int sm = swz(m);
        f2 P = up16(lds[sm]);
        f2 Q = up16(lds[sm ^ s4096]);
        f2 t = cis_rev((float)m * (1.0f / 8192.f));
        f2 w = P + cmul(Q, t);
        *(f2*)(orow + 2 * m) = mkf2(w.x * sc, w.y * sc);
    }
}

__global__ LB
void fftconv_kernel(const float* __restrict__ xin,
                    const float* __restrict__ hin,
                    float* __restrict__ out)
{
    __shared__ unsigned lds[N_FFT];   // fp16x2-packed complex: 64 KiB -> 2 blocks/CU

    const int row = blockIdx.x;
    const int tid = threadIdx.x;
    const float* xr = xin + (size_t)row * L_LEN;
    const float* hr = hin + (size_t)row * L_LEN;

    // ---- forward: fused load + q=4096&1024; 256&64; 16&4 ----
    fwd_first(lds, tid, xr, hr);
    __syncthreads();
    fwd_pair<256>(lds, tid);
    asm volatile("" ::: "memory");   // wave-local pair (1024-slot groups)
    fwd_pair<16>(lds, tid);
    __syncthreads();

    // ---- combo: finish fwd q=1, Y=XH/16, build 8 Zi per thread ----
    {
        f2 Zi0[4], Zi1[4];
        int s0[4], s1[4];
        if (tid == 0) combo_special(lds, Zi0, s0);
        else          combo_item(lds, tid, Zi0, s0);
        combo_item(lds, tid + 1024, Zi1, s1);
        __syncthreads();
#pragma unroll
        for (int k = 0; k < 4; ++k) { lds[s0[k]] = pk16(Zi0[k]); lds[s1[k]] = pk16(Zi1[k]); }
    }
    __syncthreads();

    // ---- inverse: two independent 4096-point IFFTs (512 threads) ----
    if (tid < 512) {
        inv_half<1>(lds, tid);
        asm volatile("" ::: "memory");   // wave-local within 1024-slot groups
        inv_half<16>(lds, tid);
    }
    __syncthreads();
    if (tid < 512) inv_half<256>(lds, tid);
    __syncthreads();

    // ---- final radix-2 + scale + interleaved float2 store ----
    inv_last(lds, tid, out + (size_t)row * L_LEN);
}

extern "C" void kernel_launch(void* const* d_in, const int* in_sizes, int n_in,
                              void* d_out, int out_size, void* d_ws, size_t ws_size,
                              hipStream_t stream) {
    const float* x = (const float*)d_in[0];
    const float* h = (const float*)d_in[1];
    float* out = (float*)d_out;
    const int rows = in_sizes[0] / L_LEN;   // 2048
    fftconv_kernel<<<dim3(rows), dim3(NB), 0, stream>>>(x, h, out);
}

// Round 17
// 106.727 us; speedup vs baseline: 1.0927x; 1.0927x over previous
//
#include <hip/hip_runtime.h>

#define L_LEN 8192
#define N_FFT 16384   // 2*L
#define NB    1024

#define LB __launch_bounds__(NB)

// 2-wide float vector = one complex value (re, im).
typedef float f2 __attribute__((ext_vector_type(2)));

__device__ __forceinline__ f2 mkf2(float a, float b) { f2 v; v.x = a; v.y = b; return v; }

__device__ __forceinline__ f2 cmul(f2 a, f2 w) {
    return mkf2(a.y, a.y) * mkf2(-w.y, w.x) + mkf2(a.x, a.x) * w;
}

// Native hardware sin/cos in REVOLUTIONS; all twiddle args are exact dyadic
// rationals with |rev| <= 1/4, so no range reduction is needed.
__device__ __forceinline__ void sincos_rev(float rev, float* sn, float* cs) {
    *sn = __builtin_amdgcn_sinf(rev);
    *cs = __builtin_amdgcn_cosf(rev);
}
// vector-returning variant: (cos, sin) as one f2
__device__ __forceinline__ f2 cis_rev(float rev) {
    return mkf2(__builtin_amdgcn_cosf(rev), __builtin_amdgcn_sinf(rev));
}

// bijective GF(2)-linear LDS swizzle: swz(a^b)=swz(a)^swz(b) (disjoint fields).
__host__ __device__ constexpr int swz(int i) {
    return i ^ ((((i) >> 4) ^ ((i) >> 8) ^ ((i) >> 12)) & 15);
}

// reverse 6 base-4 digits (12-bit input)
__device__ __forceinline__ int rev6(int m) {
    int r = 0;
#pragma unroll
    for (int d = 0; d < 6; ++d) { r = (r << 2) | (m & 3); m >>= 2; }
    return r;
}

// DIF radix-4 butterfly (forward), twiddles precomputed.
__device__ __forceinline__ void bfly_dif(f2& x0, f2& x1, f2& x2, f2& x3,
                                         f2 w1, f2 w2, f2 w3) {
    f2 A = x0 + x2, B = x0 - x2, C = x1 + x3, D = x1 - x3;
    f2 iD = mkf2(-D.y, D.x);
    x0 = A + C;
    x1 = cmul(B - iD, w1);
    x2 = cmul(A - C, w2);
    x3 = cmul(B + iD, w3);
}

// DIT radix-4 butterfly (inverse): twiddle inputs then combine.
__device__ __forceinline__ void bfly_dit(f2& x0, f2& x1, f2& x2, f2& x3,
                                         f2 w1, f2 w2, f2 w3) {
    f2 a1 = cmul(x1, w1), a2 = cmul(x2, w2), a3 = cmul(x3, w3);
    f2 E = x0 + a2, F = x0 - a2, G = a1 + a3, K = a1 - a3;
    f2 iK = mkf2(-K.y, K.x);
    x0 = E + G; x1 = F + iK; x2 = E - G; x3 = F - iK;
}

__device__ __forceinline__ void bfly_dif1(f2* z) {
    f2 A = z[0] + z[2], B = z[0] - z[2], C = z[1] + z[3], D = z[1] - z[3];
    f2 iD = mkf2(-D.y, D.x);
    z[0] = A + C; z[1] = B - iD; z[2] = A - C; z[3] = B + iD;
}

// Y[m] = X[m]*H[m] from Z[m] (arg Zm) and Z[N-m] (arg Zr) of z = x + i*h.
__device__ __forceinline__ f2 pwY(f2 Zm, f2 Zr) {
    f2 half = mkf2(0.5f, 0.5f);
    f2 X = half * (Zm + mkf2(Zr.x, -Zr.y));
    f2 H = half * (mkf2(Zm.y, -Zm.x) + mkf2(Zr.y, Zr.x));
    return cmul(X, H);
}

// cos/sin of 2*pi*j/16, j=0..3
#define CT0 1.0f
#define CT1 0.92387953251128674f
#define CT2 0.70710678118654752f
#define CT3 0.38268343236508977f
#define ST1 0.38268343236508977f
#define ST2 0.70710678118654752f
#define ST3 0.92387953251128674f

// First forward double-stage (q=4096,1024) fused with global load; upper
// input half is the zero-pad (x2=x3=0 in the q=4096 butterfly).
__device__ __forceinline__ void fwd_first(f2* lds, int tid,
                                          const float* __restrict__ xr,
                                          const float* __restrict__ hr) {
    f2 r[4][4];
    float snA, csA;
    sincos_rev((float)tid * (-1.0f / 16384.f), &snA, &csA);
    f2 u1 = mkf2(csA, snA);
    const f2 lad[4] = {mkf2(CT0, 0.f), mkf2(CT1, -ST1), mkf2(CT2, -ST2), mkf2(CT3, -ST3)};
#pragma unroll
    for (int jB = 0; jB < 4; ++jB) {
        const int t = tid + jB * 1024;
        f2 z0 = mkf2(xr[t], hr[t]);
        f2 z1 = mkf2(xr[t + 4096], hr[t + 4096]);
        f2 w1 = (jB == 0) ? u1 : cmul(u1, lad[jB]);
        f2 w2 = cmul(w1, w1);
        f2 w3 = cmul(w2, w1);
        f2 iz1 = mkf2(-z1.y, z1.x);
        r[0][jB] = z0 + z1;
        r[1][jB] = cmul(z0 - iz1, w1);
        r[2][jB] = cmul(z0 - z1, w2);
        r[3][jB] = cmul(z0 + iz1, w3);
    }
    float sn, cs;
    sincos_rev((float)tid * (-1.0f / 4096.f), &sn, &cs);
    f2 v1 = mkf2(cs, sn);
    f2 v2 = cmul(v1, v1);
    f2 v3 = cmul(v2, v1);
#pragma unroll
    for (int jA = 0; jA < 4; ++jA)
        bfly_dif(r[jA][0], r[jA][1], r[jA][2], r[jA][3], v1, v2, v3);

    const int sb = swz(tid);
#pragma unroll
    for (int jA = 0; jA < 4; ++jA)
#pragma unroll
        for (int jB = 0; jB < 4; ++jB)
            lds[sb ^ swz(jA * 4096 + jB * 1024)] = r[jA][jB];
}

// Fused forward DIF pair: stage q=QA then q=QA/4.
template<int QA>
__device__ __forceinline__ void fwd_pair(f2* lds, int tid) {
    constexpr int QB = QA / 4;
    const int g = tid / QB;
    const int u = tid % QB;
    const int sb = swz(g * (4 * QA) + u);
    f2 r[4][4];
#pragma unroll
    for (int jA = 0; jA < 4; ++jA)
#pragma unroll
        for (int jB = 0; jB < 4; ++jB)
            r[jA][jB] = lds[sb ^ swz(jA * QA + jB * QB)];

    {
        float sn, cs;
        sincos_rev((float)u * (-1.0f / (float)(4 * QA)), &sn, &cs);
        f2 u1 = mkf2(cs, sn);
        const f2 lad[4] = {mkf2(CT0, 0.f), mkf2(CT1, -ST1), mkf2(CT2, -ST2), mkf2(CT3, -ST3)};
#pragma unroll
        for (int jB = 0; jB < 4; ++jB) {
            f2 w1 = (jB == 0) ? u1 : cmul(u1, lad[jB]);
            f2 w2 = cmul(w1, w1);
            f2 w3 = cmul(w2, w1);
            bfly_dif(r[0][jB], r[1][jB], r[2][jB], r[3][jB], w1, w2, w3);
        }
    }
    {
        float sn, cs;
        sincos_rev((float)u * (-1.0f / (float)(4 * QB)), &sn, &cs);
        f2 v1 = mkf2(cs, sn);
        f2 v2 = cmul(v1, v1);
        f2 v3 = cmul(v2, v1);
#pragma unroll
        for (int jA = 0; jA < 4; ++jA)
            bfly_dif(r[jA][0], r[jA][1], r[jA][2], r[jA][3], v1, v2, v3);
    }

#pragma unroll
    for (int jA = 0; jA < 4; ++jA)
#pragma unroll
        for (int jB = 0; jB < 4; ++jB)
            lds[sb ^ swz(jA * QA + jB * QB)] = r[jA][jB];
}

// ---- combo item: finish fwd (q=1), Y=XH, build Zi[j] for the half-size
// inverse: Zi[j] = (Y[j]+Y[j+8192]) + i e^{2pi i j/N} (Y[j]-Y[j+8192]).
// Quad A (base 4*rev6(b)) holds bins {b,4096+b,8192+b,12288+b}; quad B holds
// their mirrors. Produces Zi at j = {b, 4096+b, 4096-b, 8192-b}, stored at
// slot (j&1)*4096 + rev6(j>>1) (digit-reversed input for the 4096-IFFT halves).
__device__ __forceinline__ void combo_item(const f2* lds, int b, f2* Zi, int* sl) {
    const int sA = swz(4 * rev6(b));
    const int sB = swz(4 * rev6(4096 - b));
    f2 A[4], B[4];
#pragma unroll
    for (int k = 0; k < 4; ++k) { A[k] = lds[sA ^ k]; B[k] = lds[sB ^ k]; }
    bfly_dif1(A);
    bfly_dif1(B);
    f2 Yb   = pwY(A[0], B[3]);   // Y[b]
    f2 Yb4  = pwY(A[1], B[2]);   // Y[4096+b]
    f2 Yb8  = pwY(A[2], B[1]);   // Y[8192+b]
    f2 Yb12 = pwY(A[3], B[0]);   // Y[12288+b]
    f2 t = cis_rev((float)b * (1.0f / 16384.f));   // (cos, sin) = e^{+2pi i b/N}
    f2 S  = Yb + Yb8,   D  = Yb - Yb8;
    f2 Sp = Yb4 + Yb12, Dp = Yb4 - Yb12;
    f2 c  = cmul(D, t);
    f2 cp = cmul(Dp, t);
    Zi[0] = mkf2(S.x - c.y,    S.y + c.x);       // j = b        : S + i c
    Zi[1] = Sp - cp;                             // j = 4096+b   : t'=it
    Zi[2] = mkf2(Sp.x + cp.x, -(Sp.y + cp.y));   // j = 4096-b   : conj(Sp+cp)
    Zi[3] = mkf2(S.x + c.y,   -S.y + c.x);       // j = 8192-b   : conj(S)+i*conj(c)
    const int sbase = (b & 1) ? 4097 : 0;        // swz(par*4096)
    const int ra = rev6(b >> 1);                 // ra % 4 == 0
    const int rc = rev6((4096 - b) >> 1);        // rc % 4 in {0,1} (bit1 free)
    sl[0] = sbase ^ swz(ra);
    sl[1] = sl[0] ^ 2;                           // rev6(2048 + (b>>1)) = ra+2
    sl[2] = sbase ^ swz(rc);
    sl[3] = sl[2] ^ 2;                           // rev6(2048 + (4096-b)>>1) = rc+2
}

// specials: j in {0, 4096} (from quad a=0) and {2048, 6144} (quad a=2)
__device__ __forceinline__ void combo_special(const f2* lds, f2* Zi, int* sl) {
    f2 z[4];
#pragma unroll
    for (int k = 0; k < 4; ++k) z[k] = lds[k];       // quad 0: bins 0,4096,8192,12288
    bfly_dif1(z);
    float Y0 = z[0].x * z[0].y;                      // Y[0] (real)
    float Y8 = z[2].x * z[2].y;                      // Y[8192] (real)
    f2 Y4096 = pwY(z[1], z[3]);
    Zi[0] = mkf2(Y0 + Y8, Y0 - Y8);          sl[0] = 0;   // Zi[0], t=1
    Zi[1] = mkf2(2.f * Y4096.x, -2.f * Y4096.y); sl[1] = 2; // Zi[4096]=2conj(Y)
    f2 w[4];
#pragma unroll
    for (int k = 0; k < 4; ++k) w[k] = lds[8 + k];   // quad a=2: bins 2048,6144,10240,14336
    bfly_dif1(w);
    f2 Y2048 = pwY(w[0], w[3]);
    f2 Y6144 = pwY(w[1], w[2]);
    f2 cj6 = mkf2(Y6144.x, -Y6144.y);
    f2 S1 = Y2048 + cj6, D1 = Y2048 - cj6;
    f2 t1 = mkf2(0.70710678118654752f, 0.70710678118654752f);    // e^{i pi/4}
    f2 c1 = cmul(D1, t1);
    Zi[2] = mkf2(S1.x - c1.y, S1.y + c1.x);  sl[2] = 1;   // Zi[2048]
    f2 cj2 = mkf2(Y2048.x, -Y2048.y);
    f2 S2 = Y6144 + cj2, D2 = Y6144 - cj2;
    f2 t2 = mkf2(-0.70710678118654752f, 0.70710678118654752f);   // e^{3i pi/4}
    f2 c2 = cmul(D2, t2);
    Zi[3] = mkf2(S2.x - c2.y, S2.y + c2.x);  sl[3] = 3;   // Zi[6144]
}

// Fused inverse DIT pair (q=QA then 4*QA) on one 4096-point half.
// th in [0,512): half h=th>>8 (slot offset 4096h), within-half thread k.
template<int QA>
__device__ __forceinline__ void inv_half(f2* lds, int th) {
    constexpr int QB = 4 * QA;
    const int h = th >> 8;
    const int k = th & 255;
    const int g = k / QA, u = k % QA;
    const int base = g * (16 * QA) + u;
    const int sb = (h ? 4097 : 0) ^ swz(base);
    f2 r[4][4];
#pragma unroll
    for (int jA = 0; jA < 4; ++jA)
#pragma unroll
        for (int jB = 0; jB < 4; ++jB)
            r[jA][jB] = lds[sb ^ swz(jA * QA + jB * QB)];

    {   // stage A (q=QA) over jA, twiddle u/(4QA)
        f2 a1;
        if constexpr (QA == 1) a1 = mkf2(1.f, 0.f);
        else { float sn, cs; sincos_rev((float)u * (1.0f / (float)(4 * QA)), &sn, &cs); a1 = mkf2(cs, sn); }
        f2 a2 = cmul(a1, a1), a3 = cmul(a2, a1);
#pragma unroll
        for (int jB = 0; jB < 4; ++jB)
            bfly_dit(r[0][jB], r[1][jB], r[2][jB], r[3][jB], a1, a2, a3);
    }
    {   // stage B (q=QB) over jB, twiddle (u + jA*QA)/(16QA)
        f2 b1;
        if constexpr (QA == 1) b1 = mkf2(1.f, 0.f);
        else { float sn, cs; sincos_rev((float)u * (1.0f / (float)(16 * QA)), &sn, &cs); b1 = mkf2(cs, sn); }
        const f2 lad[4] = {mkf2(CT0, 0.f), mkf2(CT1, ST1), mkf2(CT2, ST2), mkf2(CT3, ST3)};
#pragma unroll
        for (int jA = 0; jA < 4; ++jA) {
            f2 w1 = (jA == 0) ? b1 : cmul(b1, lad[jA]);
            f2 w2 = cmul(w1, w1), w3 = cmul(w2, w1);
            bfly_dit(r[jA][0], r[jA][1], r[jA][2], r[jA][3], w1, w2, w3);
        }
    }
#pragma unroll
    for (int jA = 0; jA < 4; ++jA)
#pragma unroll
        for (int jB = 0; jB < 4; ++jB)
            lds[sb ^ swz(jA * QA + jB * QB)] = r[jA][jB];
}

// Final radix-2 (q=4096 over the two halves) + store. Only m<4096 needed:
// S[m] = P[m] + e^{2pi i m/8192} Q[m]; out[2m]=Re*sc, out[2m+1]=Im*sc.
__device__ __forceinline__ void inv_last(const f2* lds, int tid,
                                         float* __restrict__ orow) {
    const float sc = 1.0f / (16384.f * 16384.f);   // 2^-28
#pragma unroll
    for (int i = 0; i < 4; ++i) {
        const int m = tid + i * 1024;
        const int sm = swz(m);
        f2 P = lds[sm];
        f2 Q = lds[sm ^ 4097];          // swz(4096+m)
        f2 t = cis_rev((float)m * (1.0f / 8192.f));
        f2 w = P + cmul(Q, t);
        *(f2*)(orow + 2 * m) = mkf2(w.x * sc, w.y * sc);
    }
}

__global__ LB
void fftconv_kernel(const float* __restrict__ xin,
                    const float* __restrict__ hin,
                    float* __restrict__ out)
{
    __shared__ f2 lds[N_FFT];   // 128 KiB

    const int row = blockIdx.x;
    const int tid = threadIdx.x;
    const float* xr = xin + (size_t)row * L_LEN;
    const float* hr = hin + (size_t)row * L_LEN;

    // ---- forward (unchanged): fused load + q=4096&1024; 256&64; 16&4 ----
    fwd_first(lds, tid, xr, hr);
    __syncthreads();
    fwd_pair<256>(lds, tid);
    asm volatile("" ::: "memory");
    fwd_pair<16>(lds, tid);
    __syncthreads();

    // ---- combo: finish fwd q=1, Y=XH, build 8 Zi per thread in registers.
    // ALL loads complete before the barrier; ALL Zi stores after (read-set
    // and write-set differ, so the barrier separates them globally).
    {
        f2 Zi0[4], Zi1[4];
        int s0[4], s1[4];
        if (tid == 0) combo_special(lds, Zi0, s0);
        else          combo_item(lds, tid, Zi0, s0);
        combo_item(lds, tid + 1024, Zi1, s1);
        __syncthreads();
#pragma unroll
        for (int k = 0; k < 4; ++k) { lds[s0[k]] = Zi0[k]; lds[s1[k]] = Zi1[k]; }
    }
    __syncthreads();

    // ---- inverse: two independent 4096-point IFFTs (halves), 512 threads.
    // q=1&4 and q=16&64 are wave-local within 1024-slot blocks -> fence only.
    if (tid < 512) {
        inv_half<1>(lds, tid);
        asm volatile("" ::: "memory");
        inv_half<16>(lds, tid);
    }
    __syncthreads();
    if (tid < 512) inv_half<256>(lds, tid);
    __syncthreads();

    // ---- final radix-2 + scale + interleaved float2 store ----
    inv_last(lds, tid, out + (size_t)row * L_LEN);
}

extern "C" void kernel_launch(void* const* d_in, const int* in_sizes, int n_in,
                              void* d_out, int out_size, void* d_ws, size_t ws_size,
                              hipStream_t stream) {
    const float* x = (const float*)d_in[0];
    const float* h = (const float*)d_in[1];
    float* out = (float*)d_out;
    const int rows = in_sizes[0] / L_LEN;   // 2048
    fftconv_kernel<<<dim3(rows), dim3(NB), 0, stream>>>(x, h, out);
}